// Round 14
// baseline (156.616 us; speedup 1.0000x reference)
//
#include <hip/hip_runtime.h>

typedef _Float16 half_t;
typedef _Float16 half8 __attribute__((ext_vector_type(8)));
typedef _Float16 half4v __attribute__((ext_vector_type(4)));
typedef float f32x4 __attribute__((ext_vector_type(4)));
typedef float f32x2 __attribute__((ext_vector_type(2)));

#define NB 2
#define NN 8192
#define ND 512
#define NKNN 16
#define BN (NB*NN)

// ---------------- workspace layout (bytes, all 256-aligned) ----------------
#define OFF_XH   0ull                                 // x in fp16        16.8 MB
#define OFF_VH   (OFF_XH  + (size_t)BN*ND*2)          // v in fp16        16.8 MB
#define OFF_XOH  (OFF_VH  + (size_t)BN*ND*2)          // x_out in fp16    16.8 MB
#define OFF_WVH  (OFF_XOH + (size_t)BN*ND*2)          // W_v fp16         512 KB
#define OFF_WFCH (OFF_WVH + (size_t)ND*ND*2)          // W_fc fp16        512 KB
#define OFF_XW   (OFF_WFCH+ (size_t)ND*ND*2)          // xyz+sq float4    256 KB
#define OFF_XW2  (OFF_XW  + (size_t)BN*16)            // pair-packed xyzw 256 KB
#define OFF_IDX  (OFF_XW2 + (size_t)BN*16)            // knn idx          1 MB
#define OFF_DH   (OFF_IDX + (size_t)BN*NKNN*4)        // half dists       2 MB
#define OFF_IH   (OFF_DH  + (size_t)BN*2*NKNN*4)      // half idxs        2 MB
#define OFF_WQC  (OFF_IH  + (size_t)BN*2*NKNN*4)      // col-sum W_q      2 KB
#define OFF_WKC  (OFF_WQC + 2048)                     // col-sum W_k      2 KB
#define OFF_QKB  (OFF_WKC + 2048)                     // bias sums        256 B
#define OFF_QS   (OFF_QKB + 256)                      // qsum             64 KB
#define OFF_KS   (OFF_QS  + (size_t)BN*4)             // ksum             64 KB

__device__ __forceinline__ void gload16(const void* g, void* l) {
  __builtin_amdgcn_global_load_lds((const __attribute__((address_space(1))) void*)g,
                                   (__attribute__((address_space(3))) void*)l, 16, 0, 0);
}

// ---------------- fused setup: colsum(16) | bias(1) | convw(256) | xyzw(32) ----------------
__global__ __launch_bounds__(256) void ksetup(const float* __restrict__ wqkv,
                                              const float* __restrict__ bqkv,
                                              const float* __restrict__ wfc,
                                              const float* __restrict__ xyz,
                                              float* __restrict__ wq, float* __restrict__ wk,
                                              float* __restrict__ qkb,
                                              half_t* __restrict__ wvh, half_t* __restrict__ wfch,
                                              float4* __restrict__ xw, float4* __restrict__ xw2) {
  const int blk = blockIdx.x;
  const int t = threadIdx.x;
  if (blk < 16) {                                    // W_qkv column sums (q,k halves)
    int h = blk >> 3, g = blk & 7;
    int dl = t & 63, s = t >> 6;
    const float* Wb = wqkv + (size_t)h * 512 * 512;
    int d = g * 64 + dl;
    float acc = 0.f;
    for (int e = s * 128; e < s * 128 + 128; ++e) acc += Wb[(size_t)e * 512 + d];
    __shared__ float red[4][64];
    red[s][dl] = acc;
    __syncthreads();
    if (s == 0) (h ? wk : wq)[d] = red[0][dl] + red[1][dl] + red[2][dl] + red[3][dl];
  } else if (blk == 16) {                            // bias sums (b_qkv is zeros; order-free)
    __shared__ float r0[256], r1[256];
    r0[t] = bqkv[t] + bqkv[t + 256];
    r1[t] = bqkv[512 + t] + bqkv[768 + t];
    __syncthreads();
    for (int s = 128; s; s >>= 1) {
      if (t < s) { r0[t] += r0[t + s]; r1[t] += r1[t + s]; }
      __syncthreads();
    }
    if (t == 0) { qkb[0] = r0[0]; qkb[1] = r1[0]; }
  } else if (blk < 273) {                            // weight fp16 conversion
    int i = (blk - 17) * 256 + t;
    float4 a = ((const float4*)(wqkv + 1024 * 512))[i];
    half4v ha; ha[0]=(half_t)a.x; ha[1]=(half_t)a.y; ha[2]=(half_t)a.z; ha[3]=(half_t)a.w;
    *(half4v*)(wvh + (size_t)i * 4) = ha;
    float4 c = ((const float4*)wfc)[i];
    half4v hc; hc[0]=(half_t)c.x; hc[1]=(half_t)c.y; hc[2]=(half_t)c.z; hc[3]=(half_t)c.w;
    *(half4v*)(wfch + (size_t)i * 4) = hc;
  } else {                                           // xyz -> xw (AoS) + xw2 (pair-packed)
    int p = (blk - 273) * 256 + t;
    int b = p >> 12;
    int pl = p & 4095;
    int i0 = b * NN + pl * 2;
    const float* s = xyz + (size_t)i0 * 3;
    float x0 = s[0], y0 = s[1], z0 = s[2];
    float x1 = s[3], y1 = s[4], z1 = s[5];
    float sq0 = __fadd_rn(__fadd_rn(__fmul_rn(x0, x0), __fmul_rn(y0, y0)), __fmul_rn(z0, z0));
    float sq1 = __fadd_rn(__fadd_rn(__fmul_rn(x1, x1), __fmul_rn(y1, y1)), __fmul_rn(z1, z1));
    xw[i0]     = make_float4(x0, y0, z0, sq0);
    xw[i0 + 1] = make_float4(x1, y1, z1, sq1);
    xw2[(size_t)b * NN + pl]        = make_float4(x0, x1, y0, y1);
    xw2[(size_t)b * NN + NN/2 + pl] = make_float4(z0, z1, sq0, sq1);
  }
}

// ---------------- x -> fp16 + qsum/ksum (fused; r6 proven) ----------------
__global__ __launch_bounds__(256) void kxh(const float* __restrict__ x,
                                           const float* __restrict__ wq,
                                           const float* __restrict__ wk,
                                           const float* __restrict__ qkb,
                                           half_t* __restrict__ xh,
                                           float* __restrict__ qs,
                                           float* __restrict__ ks) {
  int wid = blockIdx.x * 4 + (threadIdx.x >> 6);    // row
  int l = threadIdx.x & 63;
  size_t base = (size_t)wid * ND + l * 8;
  float4 a0 = *(const float4*)(x + base);
  float4 a1 = *(const float4*)(x + base + 4);
  half8 h;
  h[0]=(half_t)a0.x; h[1]=(half_t)a0.y; h[2]=(half_t)a0.z; h[3]=(half_t)a0.w;
  h[4]=(half_t)a1.x; h[5]=(half_t)a1.y; h[6]=(half_t)a1.z; h[7]=(half_t)a1.w;
  *(half8*)(xh + base) = h;
  float4 q0 = ((const float4*)(wq + l * 8))[0], q1 = ((const float4*)(wq + l * 8))[1];
  float4 k0 = ((const float4*)(wk + l * 8))[0], k1 = ((const float4*)(wk + l * 8))[1];
  float dq = a0.x*q0.x + a0.y*q0.y + a0.z*q0.z + a0.w*q0.w
           + a1.x*q1.x + a1.y*q1.y + a1.z*q1.z + a1.w*q1.w;
  float dk = a0.x*k0.x + a0.y*k0.y + a0.z*k0.z + a0.w*k0.w
           + a1.x*k1.x + a1.y*k1.y + a1.z*k1.z + a1.w*k1.w;
  #pragma unroll
  for (int o = 32; o; o >>= 1) { dq += __shfl_xor(dq, o); dk += __shfl_xor(dk, o); }
  if (l == 0) { qs[wid] = dq + qkb[0]; ks[wid] = dk + qkb[1]; }
}

// ---------------- KNN v7: candidate-half split + parallel-collect (grid 2048) --------------
// r13 post-mortem: occupancy was GRID-limited (1024 blocks = 4/CU exactly); LDS allows 6/CU.
// Split candidates into halves (r10 topology) but with r12's parallel-collect (the serial
// insert chains that killed r10 are gone). Block (g,h): exact lex-(d2,idx) top-16 of half h
// (2048 pairs, 8 KTILE=256 tiles) for 16 queries. kmerge combines halves exactly.
// d2 arithmetic bit-identical to validated r1-r13 stream.
#define QPW 4
#define KTILE 256
__global__ __launch_bounds__(256, 6) void kknn(const float4* __restrict__ xw,
                                               const float4* __restrict__ xw2,
                                               float* __restrict__ dhalf,
                                               int* __restrict__ ihalf) {
  __shared__ __align__(16) float4 ldsA[2][KTILE];
  __shared__ __align__(16) float4 ldsB[2][KTILE];
  __shared__ float qdl[16 * 64];                    // survivor d2   (4 waves x 4 queries)
  __shared__ int   qil[16 * 64];                    // survivor idx
  const int tid = threadIdx.x;
  const int l = tid & 63;
  const int w = tid >> 6;
  const int g = blockIdx.x >> 1;                    // query group 0..1023
  const int h = blockIdx.x & 1;                     // candidate half
  const int b = g >> 9;                             // batch
  const int qbase = (g & 511) * (4 * QPW) + w * QPW;
  const float4* xb  = xw  + (size_t)b * NN;
  const float4* xa2 = xw2 + (size_t)b * NN + h * 2048;           // A pairs of this half
  const float4* xb2 = xw2 + (size_t)b * NN + NN / 2 + h * 2048;  // B pairs of this half

#define STAGE(t, bi) do {                                                        \
    int ts_ = (t) * KTILE;                                                       \
    gload16(xa2 + ts_ + w * 64 + l, (void*)&ldsA[bi][w * 64]);                   \
    gload16(xb2 + ts_ + w * 64 + l, (void*)&ldsB[bi][w * 64]);                   \
  } while (0)

  // loop-invariant packed (splatted) query operands
  f32x2 qxx[QPW], qyy[QPW], qzz[QPW], qww[QPW];
  #pragma unroll
  for (int qi = 0; qi < QPW; ++qi) {
    float4 qp = xb[qbase + qi];
    qxx[qi] = (f32x2){qp.x, qp.x};
    qyy[qi] = (f32x2){qp.y, qp.y};
    qzz[qi] = (f32x2){qp.z, qp.z};
    qww[qi] = (f32x2){qp.w, qp.w};
  }
  const f32x2 m2 = (f32x2){-2.0f, -2.0f};

  // init survivor queues (this thread's wave's 4 queues, slot l)
  #pragma unroll
  for (int qi = 0; qi < QPW; ++qi) {
    qdl[(w * 4 + qi) * 64 + l] = __builtin_inff();
    qil[(w * 4 + qi) * 64 + l] = 0x7fffffff;
  }

  // ---- pass 1: per-lane packed min (values only) over this half ----
  f32x2 mind[QPW];
  #pragma unroll
  for (int qi = 0; qi < QPW; ++qi) mind[qi] = (f32x2){__builtin_inff(), __builtin_inff()};

  STAGE(0, 0);
  __syncthreads();
  for (int t = 0; t < 8; ++t) {
    if (t < 7) STAGE(t + 1, (t + 1) & 1);
    #pragma unroll
    for (int it = 0; it < 4; ++it) {
      int p = it * 64 + l;
      float4 A  = ldsA[t & 1][p];
      float4 Bv = ldsB[t & 1][p];
      f32x2 cx = (f32x2){A.x, A.y};
      f32x2 cy = (f32x2){A.z, A.w};
      f32x2 cz = (f32x2){Bv.x, Bv.y};
      f32x2 cw = (f32x2){Bv.z, Bv.w};
      #pragma unroll
      for (int qi = 0; qi < QPW; ++qi) {
        f32x2 dot = __builtin_elementwise_fma(qzz[qi], cz,
                      __builtin_elementwise_fma(qyy[qi], cy, qxx[qi] * cx));
        f32x2 s2 = qww[qi] + cw;
        f32x2 d2 = __builtin_elementwise_fma(m2, dot, s2);
        mind[qi] = __builtin_elementwise_min(mind[qi], d2);
      }
    }
    __syncthreads();                                 // drains next-tile stage + sync readers
  }

  // ---- merge: bitonic sort 64 lane-min values; wst = 16th smallest ----
  float wst[QPW];
  #pragma unroll
  for (int qi = 0; qi < QPW; ++qi) {
    float d = fminf(mind[qi][0], mind[qi][1]);
    #pragma unroll
    for (int k = 2; k <= 64; k <<= 1) {
      #pragma unroll
      for (int j = k >> 1; j > 0; j >>= 1) {
        float od = __shfl_xor(d, j);
        bool up = ((l & k) == 0);
        bool lower_lane = ((l & j) == 0);
        bool oless = od < d;
        bool take = (up == lower_lane) ? oless : !oless;
        if (take) d = od;
      }
    }
    wst[qi] = __shfl(d, 15);
  }

  // ---- pass 2: parallel-collect all candidates with d2 <= wst ----
  int qcnt[QPW];
  #pragma unroll
  for (int qi = 0; qi < QPW; ++qi) qcnt[qi] = 0;
  const unsigned long long below = (1ull << l) - 1;

  __syncthreads();
  STAGE(0, 0);
  __syncthreads();
  for (int t = 0; t < 8; ++t) {
    if (t < 7) STAGE(t + 1, (t + 1) & 1);
    #pragma unroll 2
    for (int it = 0; it < 4; ++it) {
      int p = it * 64 + l;
      float4 A  = ldsA[t & 1][p];
      float4 Bv = ldsB[t & 1][p];
      f32x2 cx = (f32x2){A.x, A.y};
      f32x2 cy = (f32x2){A.z, A.w};
      f32x2 cz = (f32x2){Bv.x, Bv.y};
      f32x2 cw = (f32x2){Bv.z, Bv.w};
      int ci0 = h * 4096 + (t * KTILE + p) * 2;
      #pragma unroll
      for (int qi = 0; qi < QPW; ++qi) {
        f32x2 dot = __builtin_elementwise_fma(qzz[qi], cz,
                      __builtin_elementwise_fma(qyy[qi], cy, qxx[qi] * cx));
        f32x2 s2 = qww[qi] + cw;
        f32x2 d2 = __builtin_elementwise_fma(m2, dot, s2);
        bool ok0 = d2[0] <= wst[qi];
        bool ok1 = d2[1] <= wst[qi];
        unsigned long long m0 = __ballot(ok0);
        if (m0) {
          int slot = qcnt[qi] + __popcll(m0 & below);
          if (ok0 && slot < 64) {
            qdl[(w * 4 + qi) * 64 + slot] = d2[0];
            qil[(w * 4 + qi) * 64 + slot] = ci0;
          }
          qcnt[qi] += __popcll(m0);
        }
        unsigned long long m1 = __ballot(ok1);
        if (m1) {
          int slot = qcnt[qi] + __popcll(m1 & below);
          if (ok1 && slot < 64) {
            qdl[(w * 4 + qi) * 64 + slot] = d2[1];
            qil[(w * 4 + qi) * 64 + slot] = ci0 + 1;
          }
          qcnt[qi] += __popcll(m1);
        }
      }
    }
    __syncthreads();
  }

  // ---- one 64-wide lex-(d2,idx) bitonic sort per query; lanes 0-15 emit half top-16 ----
  #pragma unroll
  for (int qi = 0; qi < QPW; ++qi) {
    float d = qdl[(w * 4 + qi) * 64 + l];
    int  ii = qil[(w * 4 + qi) * 64 + l];
    #pragma unroll
    for (int k = 2; k <= 64; k <<= 1) {
      #pragma unroll
      for (int j = k >> 1; j > 0; j >>= 1) {
        float od = __shfl_xor(d, j);
        int   oi = __shfl_xor(ii, j);
        bool up = ((l & k) == 0);
        bool lower_lane = ((l & j) == 0);
        bool oless = (od < d) || (od == d && oi < ii);
        bool take = (up == lower_lane) ? oless : !oless;
        if (take) { d = od; ii = oi; }
      }
    }
    if (l < 16) {
      size_t o = (((size_t)(b * NN + qbase + qi)) * 2 + h) * NKNN + l;
      dhalf[o] = d;
      ihalf[o] = ii;
    }
  }
#undef STAGE
}

// ---------------- merge two sorted half-top16 lists -> global top16 (bitonic 32-merge) ------
// Sequence = [A ascending | B reversed] is bitonic; 5 compare-exchange stages sort it.
// All 32 keys have distinct idx (halves disjoint) -> strict lex total order. (r10-validated)
__global__ __launch_bounds__(256) void kmerge(const float* __restrict__ dhalf,
                                              const int* __restrict__ ihalf,
                                              int* __restrict__ idxo) {
  const int l = threadIdx.x & 63;
  const int wv = threadIdx.x >> 6;
  const int q = blockIdx.x * 8 + wv * 2 + (l >> 5);   // 2 queries per wave
  const int sub = l & 31;
  const int pos = (sub < 16) ? sub : 31 - sub;
  const int hh  = (sub < 16) ? 0 : 1;
  size_t o = (((size_t)q) * 2 + hh) * NKNN + pos;
  float d = dhalf[o];
  int   i = ihalf[o];
  #pragma unroll
  for (int j = 16; j; j >>= 1) {
    float od = __shfl_xor(d, j, 32);
    int   oi = __shfl_xor(i, j, 32);
    bool oless = (od < d) || (od == d && oi < i);
    bool keepmin = ((sub & j) == 0);
    if (keepmin == oless) { d = od; i = oi; }
  }
  if (sub < 16) idxo[(size_t)q * NKNN + sub] = i;
}

// ---------------- fp16 MFMA GEMM: C[M=..,512] = A[M,512] @ Bw[512,512]^T ----------------
template <int EPI>   // 0: store half(acc+bias) ; 1: store float(acc+bias+resid)
__global__ __launch_bounds__(256) void kgemm(const half_t* __restrict__ A,
                                             const half_t* __restrict__ Bw,
                                             const float* __restrict__ bias,
                                             const float* __restrict__ resid,
                                             void* __restrict__ Cout) {
  __shared__ __align__(16) half_t As[128 * 64];
  __shared__ __align__(16) half_t Bs[128 * 64];
  const int tid = threadIdx.x;
  const int l = tid & 63;
  const int w = tid >> 6;
  const int wm = w >> 1, wn = w & 1;
  const int mt = blockIdx.x >> 2;
  const int nt = blockIdx.x & 3;
  const int lr = l & 15, lg = l >> 4;

  f32x4 acc[4][4];
  #pragma unroll
  for (int i = 0; i < 4; ++i)
    #pragma unroll
    for (int j = 0; j < 4; ++j) acc[i][j] = (f32x4){0.f, 0.f, 0.f, 0.f};

  for (int kt = 0; kt < 8; ++kt) {
    #pragma unroll
    for (int i = 0; i < 4; ++i) {
      int id = i * 256 + tid;
      int rr = id >> 3, cc = id & 7;
      gload16(A + (size_t)(mt * 128 + rr) * ND + kt * 64 + cc * 8,
              (void*)(As + (size_t)(i * 256 + w * 64) * 8));
      gload16(Bw + (size_t)(nt * 128 + rr) * ND + kt * 64 + cc * 8,
              (void*)(Bs + (size_t)(i * 256 + w * 64) * 8));
    }
    __syncthreads();
    #pragma unroll
    for (int kk = 0; kk < 2; ++kk) {
      half8 af[4], bf[4];
      #pragma unroll
      for (int mi = 0; mi < 4; ++mi)
        af[mi] = *(const half8*)(As + (wm * 64 + mi * 16 + lr) * 64 + kk * 32 + lg * 8);
      #pragma unroll
      for (int ni = 0; ni < 4; ++ni)
        bf[ni] = *(const half8*)(Bs + (wn * 64 + ni * 16 + lr) * 64 + kk * 32 + lg * 8);
      #pragma unroll
      for (int mi = 0; mi < 4; ++mi)
        #pragma unroll
        for (int ni = 0; ni < 4; ++ni)
          acc[mi][ni] = __builtin_amdgcn_mfma_f32_16x16x32_f16(af[mi], bf[ni], acc[mi][ni], 0, 0, 0);
    }
    __syncthreads();
  }

  #pragma unroll
  for (int mi = 0; mi < 4; ++mi) {
    #pragma unroll
    for (int ni = 0; ni < 4; ++ni) {
      int col = nt * 128 + wn * 64 + ni * 16 + lr;
      #pragma unroll
      for (int r4 = 0; r4 < 4; ++r4) {
        size_t row = (size_t)mt * 128 + wm * 64 + mi * 16 + lg * 4 + r4;
        float v = acc[mi][ni][r4] + bias[col];
        if (EPI == 0) ((half_t*)Cout)[row * ND + col] = (half_t)v;
        else          ((float*)Cout)[row * ND + col] = v + resid[row * ND + col];
      }
    }
  }
}

// ---------------- attention: logits -> softmax -> weighted v gather ----------------
__global__ __launch_bounds__(256) void kattn(const int* __restrict__ idx,
                                             const float* __restrict__ qs,
                                             const float* __restrict__ ks,
                                             const half_t* __restrict__ vh,
                                             half_t* __restrict__ xoh) {
  int wid = blockIdx.x * 4 + (threadIdx.x >> 6);
  int l = threadIdx.x & 63;
  int b = wid >> 13;
  int j = l & 15;
  int nb = idx[(size_t)wid * NKNN + j];
  float ksv = ks[(size_t)b * NN + nb];
  float logit = __fdiv_rn(__fmul_rn(qs[wid], ksv), 22.627416997969522f); // /sqrt(512)
  float mx = logit;
  #pragma unroll
  for (int o = 8; o; o >>= 1) mx = fmaxf(mx, __shfl_xor(mx, o, 16));
  float e = expf(logit - mx);
  float s = e;
  #pragma unroll
  for (int o = 8; o; o >>= 1) s += __shfl_xor(s, o, 16);
  float p = e / s;

  float acc[8] = {0.f, 0.f, 0.f, 0.f, 0.f, 0.f, 0.f, 0.f};
  #pragma unroll
  for (int t16 = 0; t16 < 16; ++t16) {
    float wj = __shfl(p, t16, 16);
    int ij = __shfl(nb, t16, 16);
    const half8 vv = *(const half8*)(vh + ((size_t)b * NN + ij) * ND + l * 8);
    #pragma unroll
    for (int u = 0; u < 8; ++u) acc[u] += wj * (float)vv[u];
  }
  half8 ho;
  #pragma unroll
  for (int u = 0; u < 8; ++u) ho[u] = (half_t)acc[u];
  *(half8*)(xoh + (size_t)wid * ND + l * 8) = ho;
}

// ---------------- launcher ----------------
extern "C" void kernel_launch(void* const* d_in, const int* in_sizes, int n_in,
                              void* d_out, int out_size, void* d_ws, size_t ws_size,
                              hipStream_t stream) {
  const float* x    = (const float*)d_in[0];
  const float* xyz  = (const float*)d_in[1];
  const float* wqkv = (const float*)d_in[2];
  const float* bqkv = (const float*)d_in[3];
  const float* wfc  = (const float*)d_in[4];
  const float* bfc  = (const float*)d_in[5];
  char* ws = (char*)d_ws;
  half_t* xh   = (half_t*)(ws + OFF_XH);
  half_t* vh   = (half_t*)(ws + OFF_VH);
  half_t* xoh  = (half_t*)(ws + OFF_XOH);
  half_t* wvh  = (half_t*)(ws + OFF_WVH);
  half_t* wfch = (half_t*)(ws + OFF_WFCH);
  float4* xw   = (float4*)(ws + OFF_XW);
  float4* xw2  = (float4*)(ws + OFF_XW2);
  int*    idx  = (int*)(ws + OFF_IDX);
  float*  dh   = (float*)(ws + OFF_DH);
  int*    ih   = (int*)(ws + OFF_IH);
  float*  wqc  = (float*)(ws + OFF_WQC);
  float*  wkc  = (float*)(ws + OFF_WKC);
  float*  qkb  = (float*)(ws + OFF_QKB);
  float*  qs   = (float*)(ws + OFF_QS);
  float*  ks   = (float*)(ws + OFF_KS);

  ksetup<<<dim3(305), dim3(256), 0, stream>>>(wqkv, bqkv, wfc, xyz,
                                              wqc, wkc, qkb, wvh, wfch, xw, xw2);
  kxh   <<<dim3(4096),dim3(256), 0, stream>>>(x, wqc, wkc, qkb, xh, qs, ks);
  kknn  <<<dim3(2048),dim3(256), 0, stream>>>(xw, xw2, dh, ih);
  kmerge<<<dim3(2048),dim3(256), 0, stream>>>(dh, ih, idx);
  kgemm<0><<<dim3(512),dim3(256), 0, stream>>>(xh, wvh, bqkv + 1024, (const float*)nullptr, (void*)vh);
  kattn <<<dim3(4096),dim3(256), 0, stream>>>(idx, qs, ks, vh, xoh);
  kgemm<1><<<dim3(512),dim3(256), 0, stream>>>(xoh, wfch, bfc, x, d_out);
}

// Round 15
// 142.435 us; speedup vs baseline: 1.0996x; 1.0996x over previous
//
#include <hip/hip_runtime.h>

typedef _Float16 half_t;
typedef _Float16 half8 __attribute__((ext_vector_type(8)));
typedef _Float16 half4v __attribute__((ext_vector_type(4)));
typedef float f32x4 __attribute__((ext_vector_type(4)));
typedef float f32x2 __attribute__((ext_vector_type(2)));

#define NB 2
#define NN 8192
#define ND 512
#define NKNN 16
#define BN (NB*NN)

// ---------------- workspace layout (bytes, all 256-aligned) ----------------
#define OFF_XH   0ull                                 // x in fp16        16.8 MB
#define OFF_VH   (OFF_XH  + (size_t)BN*ND*2)          // vf in fp16       16.8 MB
#define OFF_XOH  (OFF_VH  + (size_t)BN*ND*2)          // (free) -> wcomb/bcomb
#define OFF_WVH  (OFF_XOH + (size_t)BN*ND*2)          // Wv^T fp16        512 KB
#define OFF_WFCH (OFF_WVH + (size_t)ND*ND*2)          // W_fc fp16        512 KB
#define OFF_XW   (OFF_WFCH+ (size_t)ND*ND*2)          // xyz+sq float4    256 KB
#define OFF_XW2  (OFF_XW  + (size_t)BN*16)            // pair-packed xyzw 256 KB
#define OFF_IDX  (OFF_XW2 + (size_t)BN*16)            // knn idx          1 MB
#define OFF_WQC  (OFF_IDX + (size_t)BN*NKNN*4)        // col-sum W_q      2 KB
#define OFF_WKC  (OFF_WQC + 2048)                     // col-sum W_k      2 KB
#define OFF_QKB  (OFF_WKC + 2048)                     // bias sums        256 B
#define OFF_QS   (OFF_QKB + 256)                      // qsum             64 KB
#define OFF_KS   (OFF_QS  + (size_t)BN*4)             // ksum             64 KB
#define OFF_WCB  OFF_XOH                              // Wcomb fp16       512 KB
#define OFF_BCB  (OFF_XOH + (size_t)ND*ND*2)          // bcomb f32        2 KB

__device__ __forceinline__ void gload16(const void* g, void* l) {
  __builtin_amdgcn_global_load_lds((const __attribute__((address_space(1))) void*)g,
                                   (__attribute__((address_space(3))) void*)l, 16, 0, 0);
}

// ---- fused setup: colsum(16) | bias(1) | convw-fc(256) | xyzw(32) | WvT(64) | bcomb(64) ----
__global__ __launch_bounds__(256) void ksetup(const float* __restrict__ wqkv,
                                              const float* __restrict__ bqkv,
                                              const float* __restrict__ wfc,
                                              const float* __restrict__ xyz,
                                              float* __restrict__ wq, float* __restrict__ wk,
                                              float* __restrict__ qkb,
                                              half_t* __restrict__ wvth, half_t* __restrict__ wfch,
                                              float4* __restrict__ xw, float4* __restrict__ xw2,
                                              float* __restrict__ bcomb) {
  const int blk = blockIdx.x;
  const int t = threadIdx.x;
  if (blk < 16) {                                    // W_qkv column sums (q,k halves)
    int h = blk >> 3, g = blk & 7;
    int dl = t & 63, s = t >> 6;
    const float* Wb = wqkv + (size_t)h * 512 * 512;
    int d = g * 64 + dl;
    float acc = 0.f;
    for (int e = s * 128; e < s * 128 + 128; ++e) acc += Wb[(size_t)e * 512 + d];
    __shared__ float red[4][64];
    red[s][dl] = acc;
    __syncthreads();
    if (s == 0) (h ? wk : wq)[d] = red[0][dl] + red[1][dl] + red[2][dl] + red[3][dl];
  } else if (blk == 16) {                            // q/k bias sums
    __shared__ float r0[256], r1[256];
    r0[t] = bqkv[t] + bqkv[t + 256];
    r1[t] = bqkv[512 + t] + bqkv[768 + t];
    __syncthreads();
    for (int s = 128; s; s >>= 1) {
      if (t < s) { r0[t] += r0[t + s]; r1[t] += r1[t + s]; }
      __syncthreads();
    }
    if (t == 0) { qkb[0] = r0[0]; qkb[1] = r1[0]; }
  } else if (blk < 273) {                            // W_fc -> fp16
    int i = (blk - 17) * 256 + t;
    float4 c = ((const float4*)wfc)[i];
    half4v hc; hc[0]=(half_t)c.x; hc[1]=(half_t)c.y; hc[2]=(half_t)c.z; hc[3]=(half_t)c.w;
    *(half4v*)(wfch + (size_t)i * 4) = hc;
  } else if (blk < 305) {                            // xyz -> xw (AoS) + xw2 (pair-packed)
    int p = (blk - 273) * 256 + t;
    int b = p >> 12;
    int pl = p & 4095;
    int i0 = b * NN + pl * 2;
    const float* s = xyz + (size_t)i0 * 3;
    float x0 = s[0], y0 = s[1], z0 = s[2];
    float x1 = s[3], y1 = s[4], z1 = s[5];
    float sq0 = __fadd_rn(__fadd_rn(__fmul_rn(x0, x0), __fmul_rn(y0, y0)), __fmul_rn(z0, z0));
    float sq1 = __fadd_rn(__fadd_rn(__fmul_rn(x1, x1), __fmul_rn(y1, y1)), __fmul_rn(z1, z1));
    xw[i0]     = make_float4(x0, y0, z0, sq0);
    xw[i0 + 1] = make_float4(x1, y1, z1, sq1);
    xw2[(size_t)b * NN + pl]        = make_float4(x0, x1, y0, y1);
    xw2[(size_t)b * NN + NN/2 + pl] = make_float4(z0, z1, sq0, sq1);
  } else if (blk < 369) {                            // Wv^T fp16: wvth[cin][vo] = Wv[vo][cin]
    int tile = blk - 305, tr = tile >> 3, tc = tile & 7;
    __shared__ float tbuf[64][65];
    int rr = t >> 6, cc = t & 63;
    #pragma unroll 4
    for (int p = 0; p < 16; ++p)
      tbuf[p * 4 + rr][cc] = wqkv[(size_t)(1024 + tc * 64 + p * 4 + rr) * 512 + tr * 64 + cc];
    __syncthreads();
    #pragma unroll 4
    for (int p = 0; p < 16; ++p)
      wvth[(size_t)(tr * 64 + p * 4 + rr) * 512 + tc * 64 + cc] = (half_t)tbuf[cc][p * 4 + rr];
  } else {                                           // bcomb[e] = sum_vo Wfc[e,vo]*bv[vo]
    int base = (blk - 369) * 8;
    int wv_ = t >> 6, l_ = t & 63;
    #pragma unroll
    for (int rr = 0; rr < 2; ++rr) {
      int e = base + wv_ * 2 + rr;
      float acc = 0.f;
      #pragma unroll
      for (int it = 0; it < 8; ++it)
        acc += wfc[(size_t)e * 512 + it * 64 + l_] * bqkv[1024 + it * 64 + l_];
      #pragma unroll
      for (int o = 32; o; o >>= 1) acc += __shfl_xor(acc, o);
      if (l_ == 0) bcomb[e] = acc;
    }
  }
}

// ---------------- x -> fp16 + qsum/ksum (fused; r6 proven) ----------------
__global__ __launch_bounds__(256) void kxh(const float* __restrict__ x,
                                           const float* __restrict__ wq,
                                           const float* __restrict__ wk,
                                           const float* __restrict__ qkb,
                                           half_t* __restrict__ xh,
                                           float* __restrict__ qs,
                                           float* __restrict__ ks) {
  int wid = blockIdx.x * 4 + (threadIdx.x >> 6);    // row
  int l = threadIdx.x & 63;
  size_t base = (size_t)wid * ND + l * 8;
  float4 a0 = *(const float4*)(x + base);
  float4 a1 = *(const float4*)(x + base + 4);
  half8 h;
  h[0]=(half_t)a0.x; h[1]=(half_t)a0.y; h[2]=(half_t)a0.z; h[3]=(half_t)a0.w;
  h[4]=(half_t)a1.x; h[5]=(half_t)a1.y; h[6]=(half_t)a1.z; h[7]=(half_t)a1.w;
  *(half8*)(xh + base) = h;
  float4 q0 = ((const float4*)(wq + l * 8))[0], q1 = ((const float4*)(wq + l * 8))[1];
  float4 k0 = ((const float4*)(wk + l * 8))[0], k1 = ((const float4*)(wk + l * 8))[1];
  float dq = a0.x*q0.x + a0.y*q0.y + a0.z*q0.z + a0.w*q0.w
           + a1.x*q1.x + a1.y*q1.y + a1.z*q1.z + a1.w*q1.w;
  float dk = a0.x*k0.x + a0.y*k0.y + a0.z*k0.z + a0.w*k0.w
           + a1.x*k1.x + a1.y*k1.y + a1.z*k1.z + a1.w*k1.w;
  #pragma unroll
  for (int o = 32; o; o >>= 1) { dq += __shfl_xor(dq, o); dk += __shfl_xor(dk, o); }
  if (l == 0) { qs[wid] = dq + qkb[0]; ks[wid] = dk + qkb[1]; }
}

// ---------------- KNN v5 (r12 verbatim, 65.7us proven) ----------------
#define QPW 4
#define KTILE 512
__global__ __launch_bounds__(256, 4) void kknn(const float4* __restrict__ xw,
                                               const float4* __restrict__ xw2,
                                               int* __restrict__ idxo) {
  __shared__ __align__(16) float4 ldsA[2][KTILE];
  __shared__ __align__(16) float4 ldsB[2][KTILE];
  __shared__ float qdl[16 * 64];                    // survivor d2   (4 waves x 4 queries)
  __shared__ int   qil[16 * 64];                    // survivor idx
  const int tid = threadIdx.x;
  const int l = tid & 63;
  const int w = tid >> 6;
  const int b = blockIdx.x >> 9;
  const int qbase = (blockIdx.x & 511) * (4 * QPW) + w * QPW;
  const float4* xb  = xw  + (size_t)b * NN;
  const float4* xa2 = xw2 + (size_t)b * NN;         // A pairs (x0,x1,y0,y1)
  const float4* xb2 = xa2 + NN / 2;                 // B pairs (z0,z1,sq0,sq1)

#define STAGE(t, bi) do {                                                        \
    int ts_ = (t) * KTILE;                                                       \
    gload16(xa2 + ts_ +       w * 64 + l, (void*)&ldsA[bi][      w * 64]);       \
    gload16(xa2 + ts_ + 256 + w * 64 + l, (void*)&ldsA[bi][256 + w * 64]);       \
    gload16(xb2 + ts_ +       w * 64 + l, (void*)&ldsB[bi][      w * 64]);       \
    gload16(xb2 + ts_ + 256 + w * 64 + l, (void*)&ldsB[bi][256 + w * 64]);       \
  } while (0)

  // loop-invariant packed (splatted) query operands
  f32x2 qxx[QPW], qyy[QPW], qzz[QPW], qww[QPW];
  #pragma unroll
  for (int qi = 0; qi < QPW; ++qi) {
    float4 qp = xb[qbase + qi];
    qxx[qi] = (f32x2){qp.x, qp.x};
    qyy[qi] = (f32x2){qp.y, qp.y};
    qzz[qi] = (f32x2){qp.z, qp.z};
    qww[qi] = (f32x2){qp.w, qp.w};
  }
  const f32x2 m2 = (f32x2){-2.0f, -2.0f};

  // init survivor queues
  #pragma unroll
  for (int qi = 0; qi < QPW; ++qi) {
    qdl[(w * 4 + qi) * 64 + l] = __builtin_inff();
    qil[(w * 4 + qi) * 64 + l] = 0x7fffffff;
  }

  // ---- pass 1: per-lane packed min (values only) ----
  f32x2 mind[QPW];
  #pragma unroll
  for (int qi = 0; qi < QPW; ++qi) mind[qi] = (f32x2){__builtin_inff(), __builtin_inff()};

  STAGE(0, 0);
  __syncthreads();
  for (int t = 0; t < 8; ++t) {
    if (t < 7) STAGE(t + 1, (t + 1) & 1);
    #pragma unroll
    for (int it = 0; it < 8; ++it) {
      int p = it * 64 + l;
      float4 A  = ldsA[t & 1][p];
      float4 Bv = ldsB[t & 1][p];
      f32x2 cx = (f32x2){A.x, A.y};
      f32x2 cy = (f32x2){A.z, A.w};
      f32x2 cz = (f32x2){Bv.x, Bv.y};
      f32x2 cw = (f32x2){Bv.z, Bv.w};
      #pragma unroll
      for (int qi = 0; qi < QPW; ++qi) {
        f32x2 dot = __builtin_elementwise_fma(qzz[qi], cz,
                      __builtin_elementwise_fma(qyy[qi], cy, qxx[qi] * cx));
        f32x2 s2 = qww[qi] + cw;
        f32x2 d2 = __builtin_elementwise_fma(m2, dot, s2);
        mind[qi] = __builtin_elementwise_min(mind[qi], d2);
      }
    }
    __syncthreads();
  }

  // ---- merge: bitonic sort 64 lane-min values; wst = 16th smallest ----
  float wst[QPW];
  #pragma unroll
  for (int qi = 0; qi < QPW; ++qi) {
    float d = fminf(mind[qi][0], mind[qi][1]);
    #pragma unroll
    for (int k = 2; k <= 64; k <<= 1) {
      #pragma unroll
      for (int j = k >> 1; j > 0; j >>= 1) {
        float od = __shfl_xor(d, j);
        bool up = ((l & k) == 0);
        bool lower_lane = ((l & j) == 0);
        bool oless = od < d;
        bool take = (up == lower_lane) ? oless : !oless;
        if (take) d = od;
      }
    }
    wst[qi] = __shfl(d, 15);
  }

  // ---- pass 2: parallel-collect all candidates with d2 <= wst ----
  int qcnt[QPW];
  #pragma unroll
  for (int qi = 0; qi < QPW; ++qi) qcnt[qi] = 0;
  const unsigned long long below = (1ull << l) - 1;

  __syncthreads();
  STAGE(0, 0);
  __syncthreads();
  for (int t = 0; t < 8; ++t) {
    if (t < 7) STAGE(t + 1, (t + 1) & 1);
    #pragma unroll 2
    for (int it = 0; it < 8; ++it) {
      int p = it * 64 + l;
      float4 A  = ldsA[t & 1][p];
      float4 Bv = ldsB[t & 1][p];
      f32x2 cx = (f32x2){A.x, A.y};
      f32x2 cy = (f32x2){A.z, A.w};
      f32x2 cz = (f32x2){Bv.x, Bv.y};
      f32x2 cw = (f32x2){Bv.z, Bv.w};
      int ci0 = (t * KTILE + p) * 2;
      #pragma unroll
      for (int qi = 0; qi < QPW; ++qi) {
        f32x2 dot = __builtin_elementwise_fma(qzz[qi], cz,
                      __builtin_elementwise_fma(qyy[qi], cy, qxx[qi] * cx));
        f32x2 s2 = qww[qi] + cw;
        f32x2 d2 = __builtin_elementwise_fma(m2, dot, s2);
        bool ok0 = d2[0] <= wst[qi];
        bool ok1 = d2[1] <= wst[qi];
        unsigned long long m0 = __ballot(ok0);
        if (m0) {
          int slot = qcnt[qi] + __popcll(m0 & below);
          if (ok0 && slot < 64) {
            qdl[(w * 4 + qi) * 64 + slot] = d2[0];
            qil[(w * 4 + qi) * 64 + slot] = ci0;
          }
          qcnt[qi] += __popcll(m0);
        }
        unsigned long long m1 = __ballot(ok1);
        if (m1) {
          int slot = qcnt[qi] + __popcll(m1 & below);
          if (ok1 && slot < 64) {
            qdl[(w * 4 + qi) * 64 + slot] = d2[1];
            qil[(w * 4 + qi) * 64 + slot] = ci0 + 1;
          }
          qcnt[qi] += __popcll(m1);
        }
      }
    }
    __syncthreads();
  }

  // ---- one 64-wide lex-(d2,idx) bitonic sort per query; lanes 0-15 emit top-16 ----
  #pragma unroll
  for (int qi = 0; qi < QPW; ++qi) {
    float d = qdl[(w * 4 + qi) * 64 + l];
    int  ii = qil[(w * 4 + qi) * 64 + l];
    #pragma unroll
    for (int k = 2; k <= 64; k <<= 1) {
      #pragma unroll
      for (int j = k >> 1; j > 0; j >>= 1) {
        float od = __shfl_xor(d, j);
        int   oi = __shfl_xor(ii, j);
        bool up = ((l & k) == 0);
        bool lower_lane = ((l & j) == 0);
        bool oless = (od < d) || (od == d && oi < ii);
        bool take = (up == lower_lane) ? oless : !oless;
        if (take) { d = od; ii = oi; }
      }
    }
    if (l < 16) idxo[((size_t)b * NN + qbase + qi) * NKNN + l] = ii;
  }
#undef STAGE
}

// ---------------- fp16 MFMA GEMM: C = A @ Bw^T (+bias) ----------------
// EPI 0: half(acc+bias) ; EPI 2: half(acc), no bias (Wcomb)
template <int EPI>
__global__ __launch_bounds__(256) void kgemm(const half_t* __restrict__ A,
                                             const half_t* __restrict__ Bw,
                                             const float* __restrict__ bias,
                                             void* __restrict__ Cout) {
  __shared__ __align__(16) half_t As[128 * 64];
  __shared__ __align__(16) half_t Bs[128 * 64];
  const int tid = threadIdx.x;
  const int l = tid & 63;
  const int w = tid >> 6;
  const int wm = w >> 1, wn = w & 1;
  const int mt = blockIdx.x >> 2;
  const int nt = blockIdx.x & 3;
  const int lr = l & 15, lg = l >> 4;

  f32x4 acc[4][4];
  #pragma unroll
  for (int i = 0; i < 4; ++i)
    #pragma unroll
    for (int j = 0; j < 4; ++j) acc[i][j] = (f32x4){0.f, 0.f, 0.f, 0.f};

  for (int kt = 0; kt < 8; ++kt) {
    #pragma unroll
    for (int i = 0; i < 4; ++i) {
      int id = i * 256 + tid;
      int rr = id >> 3, cc = id & 7;
      gload16(A + (size_t)(mt * 128 + rr) * ND + kt * 64 + cc * 8,
              (void*)(As + (size_t)(i * 256 + w * 64) * 8));
      gload16(Bw + (size_t)(nt * 128 + rr) * ND + kt * 64 + cc * 8,
              (void*)(Bs + (size_t)(i * 256 + w * 64) * 8));
    }
    __syncthreads();
    #pragma unroll
    for (int kk = 0; kk < 2; ++kk) {
      half8 af[4], bf[4];
      #pragma unroll
      for (int mi = 0; mi < 4; ++mi)
        af[mi] = *(const half8*)(As + (wm * 64 + mi * 16 + lr) * 64 + kk * 32 + lg * 8);
      #pragma unroll
      for (int ni = 0; ni < 4; ++ni)
        bf[ni] = *(const half8*)(Bs + (wn * 64 + ni * 16 + lr) * 64 + kk * 32 + lg * 8);
      #pragma unroll
      for (int mi = 0; mi < 4; ++mi)
        #pragma unroll
        for (int ni = 0; ni < 4; ++ni)
          acc[mi][ni] = __builtin_amdgcn_mfma_f32_16x16x32_f16(af[mi], bf[ni], acc[mi][ni], 0, 0, 0);
    }
    __syncthreads();
  }

  #pragma unroll
  for (int mi = 0; mi < 4; ++mi) {
    #pragma unroll
    for (int ni = 0; ni < 4; ++ni) {
      int col = nt * 128 + wn * 64 + ni * 16 + lr;
      #pragma unroll
      for (int r4 = 0; r4 < 4; ++r4) {
        size_t row = (size_t)mt * 128 + wm * 64 + mi * 16 + lg * 4 + r4;
        if (EPI == 0) ((half_t*)Cout)[row * ND + col] = (half_t)(acc[mi][ni][r4] + bias[col]);
        else          ((half_t*)Cout)[row * ND + col] = (half_t)acc[mi][ni][r4];
      }
    }
  }
}

// ---- attention: softmax logits -> weighted vf gather -> + bfc + x -> f32 out (gemm1 fused away)
__global__ __launch_bounds__(256) void kattn(const int* __restrict__ idx,
                                             const float* __restrict__ qs,
                                             const float* __restrict__ ks,
                                             const half_t* __restrict__ vfh,
                                             const float* __restrict__ bfc,
                                             const float* __restrict__ x,
                                             float* __restrict__ out) {
  int wid = blockIdx.x * 4 + (threadIdx.x >> 6);
  int l = threadIdx.x & 63;
  int b = wid >> 13;
  int j = l & 15;
  int nb = idx[(size_t)wid * NKNN + j];
  float ksv = ks[(size_t)b * NN + nb];
  float logit = __fdiv_rn(__fmul_rn(qs[wid], ksv), 22.627416997969522f); // /sqrt(512)
  float mx = logit;
  #pragma unroll
  for (int o = 8; o; o >>= 1) mx = fmaxf(mx, __shfl_xor(mx, o, 16));
  float e = expf(logit - mx);
  float s = e;
  #pragma unroll
  for (int o = 8; o; o >>= 1) s += __shfl_xor(s, o, 16);
  float p = e / s;

  float acc[8] = {0.f, 0.f, 0.f, 0.f, 0.f, 0.f, 0.f, 0.f};
  #pragma unroll
  for (int t16 = 0; t16 < 16; ++t16) {
    float wj = __shfl(p, t16, 16);
    int ij = __shfl(nb, t16, 16);
    const half8 vv = *(const half8*)(vfh + ((size_t)b * NN + ij) * ND + l * 8);
    #pragma unroll
    for (int u = 0; u < 8; ++u) acc[u] += wj * (float)vv[u];
  }
  size_t base = (size_t)wid * ND + l * 8;
  float4 xa0 = *(const float4*)(x + base);
  float4 xa1 = *(const float4*)(x + base + 4);
  float4 bf0 = *(const float4*)(bfc + l * 8);
  float4 bf1 = *(const float4*)(bfc + l * 8 + 4);
  float4 o0 = make_float4(acc[0] + bf0.x + xa0.x, acc[1] + bf0.y + xa0.y,
                          acc[2] + bf0.z + xa0.z, acc[3] + bf0.w + xa0.w);
  float4 o1 = make_float4(acc[4] + bf1.x + xa1.x, acc[5] + bf1.y + xa1.y,
                          acc[6] + bf1.z + xa1.z, acc[7] + bf1.w + xa1.w);
  *(float4*)(out + base) = o0;
  *(float4*)(out + base + 4) = o1;
}

// ---------------- launcher ----------------
extern "C" void kernel_launch(void* const* d_in, const int* in_sizes, int n_in,
                              void* d_out, int out_size, void* d_ws, size_t ws_size,
                              hipStream_t stream) {
  const float* x    = (const float*)d_in[0];
  const float* xyz  = (const float*)d_in[1];
  const float* wqkv = (const float*)d_in[2];
  const float* bqkv = (const float*)d_in[3];
  const float* wfc  = (const float*)d_in[4];
  const float* bfc  = (const float*)d_in[5];
  char* ws = (char*)d_ws;
  half_t* xh    = (half_t*)(ws + OFF_XH);
  half_t* vfh   = (half_t*)(ws + OFF_VH);
  half_t* wvth  = (half_t*)(ws + OFF_WVH);
  half_t* wfch  = (half_t*)(ws + OFF_WFCH);
  half_t* wcomb = (half_t*)(ws + OFF_WCB);
  float*  bcomb = (float*)(ws + OFF_BCB);
  float4* xw    = (float4*)(ws + OFF_XW);
  float4* xw2   = (float4*)(ws + OFF_XW2);
  int*    idx   = (int*)(ws + OFF_IDX);
  float*  wqc   = (float*)(ws + OFF_WQC);
  float*  wkc   = (float*)(ws + OFF_WKC);
  float*  qkb   = (float*)(ws + OFF_QKB);
  float*  qs    = (float*)(ws + OFF_QS);
  float*  ks    = (float*)(ws + OFF_KS);

  ksetup<<<dim3(433), dim3(256), 0, stream>>>(wqkv, bqkv, wfc, xyz,
                                              wqc, wkc, qkb, wvth, wfch, xw, xw2, bcomb);
  kxh     <<<dim3(4096),dim3(256), 0, stream>>>(x, wqc, wkc, qkb, xh, qs, ks);
  kknn    <<<dim3(1024),dim3(256), 0, stream>>>(xw, xw2, idx);
  kgemm<2><<<dim3(16),  dim3(256), 0, stream>>>(wfch, wvth, (const float*)nullptr, (void*)wcomb);
  kgemm<0><<<dim3(512), dim3(256), 0, stream>>>(xh, wcomb, bcomb, (void*)vfh);
  kattn   <<<dim3(4096),dim3(256), 0, stream>>>(idx, qs, ks, vfh, bfc, x, (float*)d_out);
}